// Round 4
// baseline (651.904 us; speedup 1.0000x reference)
//
#include <hip/hip_runtime.h>
#include <hip/hip_bf16.h>

typedef __attribute__((ext_vector_type(8))) short short8;
typedef __attribute__((ext_vector_type(4))) float f32x4;

#define NB 65536
#define EPSV 1e-5f

// ---- workspace layout (byte offsets, all 256-aligned) ----
#define OFF_SUM1   0u          // 320 f32
#define OFF_SQ1    1280u       // 320 f32
#define OFF_SUM2   2560u       // 128 f32
#define OFF_SQ2    3072u       // 128 f32  (stats end at 3584)
#define OFF_A1     4096u       // 320 f32
#define OFF_C1     5376u       // 320 f32
#define OFF_A2     6656u       // 128 f32
#define OFF_C2     7168u       // 128 f32
#define OFF_W1BF   8192u       // [320][800] bf16 = 512000 B (rows>=300, cols>=784 zero)
#define OFF_W2BF   524288u     // [112][320] bf16 = 71680 B  (rows>=100, cols>=300 zero)
#define OFF_W3BF   602112u     // [16][112]  bf16 = 3584 B   (rows>=10,  cols>=100 zero)
#define OFF_H1     1048576u    // [65536][304] bf16 = 39845888 B
#define OFF_H2     41943040u   // [65536][112] bf16 = 14680064 B  (ws end ~56.6 MB)

__device__ __forceinline__ float b2f(unsigned short u) {
  return __uint_as_float(((unsigned int)u) << 16);
}
__device__ __forceinline__ unsigned short f2b(float f) {
  __hip_bfloat16 h = __float2bfloat16(f);   // RNE
  return __builtin_bit_cast(unsigned short, h);
}

// ---------------- prep: pack weights to zero-padded bf16 ----------------
__global__ void k_prep(const float* __restrict__ W1, const float* __restrict__ W2,
                       const float* __restrict__ W3, unsigned short* __restrict__ w1bf,
                       unsigned short* __restrict__ w2bf, unsigned short* __restrict__ w3bf) {
  int i = blockIdx.x * blockDim.x + threadIdx.x;
  const int N1 = 320 * 800, N2 = 112 * 320, N3 = 16 * 112;
  if (i < N1) {
    int r = i / 800, c = i % 800;
    w1bf[i] = (r < 300 && c < 784) ? f2b(W1[r * 784 + c]) : (unsigned short)0;
  } else if (i < N1 + N2) {
    int j = i - N1; int r = j / 320, c = j % 320;
    w2bf[j] = (r < 100 && c < 300) ? f2b(W2[r * 300 + c]) : (unsigned short)0;
  } else if (i < N1 + N2 + N3) {
    int j = i - N1 - N2; int r = j / 112, c = j % 112;
    w3bf[j] = (r < 10 && c < 100) ? f2b(W3[r * 100 + c]) : (unsigned short)0;
  }
}

// ---------------- finalize BN stats -> per-feature affine ----------------
__global__ void k_finalize(const float* __restrict__ sum, const float* __restrict__ sq,
                           const float* __restrict__ g, const float* __restrict__ be,
                           float* __restrict__ a, float* __restrict__ c, int F, int Fpad) {
  int f = blockIdx.x * blockDim.x + threadIdx.x;
  if (f >= Fpad) return;
  if (f < F) {
    float mean = sum[f] * (1.f / 65536.f);
    float var  = sq[f]  * (1.f / 65536.f) - mean * mean;   // biased, matches jnp.var
    float av   = g[f] * rsqrtf(var + EPSV);
    a[f] = av;
    c[f] = be[f] - mean * av;
  } else { a[f] = 0.f; c[f] = 0.f; }
}

// ---------------- GEMM1: h1 = relu(x @ W1^T + b1), + stats ----------------
// block = 512 thr (8 waves, 2M x 4N); BM=128 rows, BN=320 cols; K=784
__global__ __launch_bounds__(512, 2) void k_gemm1(
    const float* __restrict__ x, const float* __restrict__ b1,
    const unsigned short* __restrict__ w1bf,
    unsigned short* __restrict__ h1,
    float* __restrict__ sum1, float* __restrict__ sq1) {
  const int lane = threadIdx.x & 63, wid = threadIdx.x >> 6;
  const int wm = wid >> 2, wn = wid & 3;
  const int r = lane & 15, g = lane >> 4;
  const long rowbase = (long)blockIdx.x * 128 + wm * 64;

  f32x4 acc[4][5] = {};

  const float* xp = x + (rowbase + r) * 784 + g * 8;
  const unsigned short* bp = w1bf + (long)(wn * 80 + r) * 800 + g * 8;

  for (int k0 = 0; k0 < 784; k0 += 32) {
    short8 af[4];
    if ((k0 + g * 8) < 784) {
#pragma unroll
      for (int mt = 0; mt < 4; ++mt) {
        const float* p = xp + (long)mt * 16 * 784 + k0;
        float4 f0 = *reinterpret_cast<const float4*>(p);
        float4 f1 = *reinterpret_cast<const float4*>(p + 4);
        short8 a;
        a[0] = f2b(f0.x); a[1] = f2b(f0.y); a[2] = f2b(f0.z); a[3] = f2b(f0.w);
        a[4] = f2b(f1.x); a[5] = f2b(f1.y); a[6] = f2b(f1.z); a[7] = f2b(f1.w);
        af[mt] = a;
      }
    } else {
#pragma unroll
      for (int mt = 0; mt < 4; ++mt) af[mt] = (short8)(short)0;
    }
    short8 bfr[5];
#pragma unroll
    for (int nt = 0; nt < 5; ++nt)
      bfr[nt] = *reinterpret_cast<const short8*>(bp + (long)nt * 16 * 800 + k0);
#pragma unroll
    for (int mt = 0; mt < 4; ++mt)
#pragma unroll
      for (int nt = 0; nt < 5; ++nt)
        acc[mt][nt] = __builtin_amdgcn_mfma_f32_16x16x32_bf16(af[mt], bfr[nt], acc[mt][nt], 0, 0, 0);
  }

  // epilogue: +bias, relu, store bf16, per-feature stats
#pragma unroll
  for (int nt = 0; nt < 5; ++nt) {
    int col = wn * 80 + nt * 16 + r;
    float bias = (col < 300) ? b1[col] : 0.f;
    float ps = 0.f, pq = 0.f;
#pragma unroll
    for (int mt = 0; mt < 4; ++mt) {
#pragma unroll
      for (int v = 0; v < 4; ++v) {
        float val = fmaxf(acc[mt][nt][v] + bias, 0.f);   // padded cols: 0+0 -> 0
        long row = rowbase + mt * 16 + g * 4 + v;
        if (col < 304) h1[row * 304 + col] = f2b(val);
        ps += val; pq += val * val;                       // padded cols add 0
      }
    }
    float ts = ps + __shfl_xor(ps, 16, 64); ts += __shfl_xor(ts, 32, 64);
    float tq = pq + __shfl_xor(pq, 16, 64); tq += __shfl_xor(tq, 32, 64);
    if (g == 0) { atomicAdd(&sum1[col], ts); atomicAdd(&sq1[col], tq); }
  }
}

// ------- GEMM2: h2 = relu( ((a1*h1+c1)*s1+m1) @ W2^T + b2 ), + stats -------
// block = 512 thr (8 waves x 16 rows); per wave full N (7 tiles of 16); K=300->320
__global__ __launch_bounds__(512, 2) void k_gemm2(
    const unsigned short* __restrict__ h1, const float* __restrict__ s1,
    const float* __restrict__ m1, const float* __restrict__ a1,
    const float* __restrict__ c1, const float* __restrict__ b2,
    const unsigned short* __restrict__ w2bf,
    unsigned short* __restrict__ h2,
    float* __restrict__ sum2, float* __restrict__ sq2) {
  const int lane = threadIdx.x & 63, wid = threadIdx.x >> 6;
  const int r = lane & 15, g = lane >> 4;
  const long rowb = (long)blockIdx.x * 128 + wid * 16;
  const long row = rowb + r;

  f32x4 acc[7] = {};
  const unsigned short* hp = h1 + row * 304 + g * 8;
  const float* sp = s1 + row * 300 + g * 8;
  const float* mp = m1 + row * 300 + g * 8;
  const unsigned short* wp = w2bf + (long)r * 320 + g * 8;

  for (int k0 = 0; k0 < 300; k0 += 32) {
    int kb = k0 + g * 8;
    short8 af = (short8)(short)0;
    if (kb + 8 <= 300) {
      short8 h8 = *reinterpret_cast<const short8*>(hp + k0);
      float4 sA = *reinterpret_cast<const float4*>(sp + k0);
      float4 sB = *reinterpret_cast<const float4*>(sp + k0 + 4);
      float4 mA = *reinterpret_cast<const float4*>(mp + k0);
      float4 mB = *reinterpret_cast<const float4*>(mp + k0 + 4);
      float4 aA = *reinterpret_cast<const float4*>(a1 + kb);
      float4 aB = *reinterpret_cast<const float4*>(a1 + kb + 4);
      float4 cA = *reinterpret_cast<const float4*>(c1 + kb);
      float4 cB = *reinterpret_cast<const float4*>(c1 + kb + 4);
      af[0] = f2b((aA.x * b2f((unsigned short)h8[0]) + cA.x) * sA.x + mA.x);
      af[1] = f2b((aA.y * b2f((unsigned short)h8[1]) + cA.y) * sA.y + mA.y);
      af[2] = f2b((aA.z * b2f((unsigned short)h8[2]) + cA.z) * sA.z + mA.z);
      af[3] = f2b((aA.w * b2f((unsigned short)h8[3]) + cA.w) * sA.w + mA.w);
      af[4] = f2b((aB.x * b2f((unsigned short)h8[4]) + cB.x) * sB.x + mB.x);
      af[5] = f2b((aB.y * b2f((unsigned short)h8[5]) + cB.y) * sB.y + mB.y);
      af[6] = f2b((aB.z * b2f((unsigned short)h8[6]) + cB.z) * sB.z + mB.z);
      af[7] = f2b((aB.w * b2f((unsigned short)h8[7]) + cB.w) * sB.w + mB.w);
    } else if (kb < 300) {                    // kb == 296: 4 valid elements
      short8 h8 = *reinterpret_cast<const short8*>(hp + k0);   // cols 296..303 exist in h1
      float4 sA = *reinterpret_cast<const float4*>(sp + k0);
      float4 mA = *reinterpret_cast<const float4*>(mp + k0);
      float4 aA = *reinterpret_cast<const float4*>(a1 + kb);
      float4 cA = *reinterpret_cast<const float4*>(c1 + kb);
      af[0] = f2b((aA.x * b2f((unsigned short)h8[0]) + cA.x) * sA.x + mA.x);
      af[1] = f2b((aA.y * b2f((unsigned short)h8[1]) + cA.y) * sA.y + mA.y);
      af[2] = f2b((aA.z * b2f((unsigned short)h8[2]) + cA.z) * sA.z + mA.z);
      af[3] = f2b((aA.w * b2f((unsigned short)h8[3]) + cA.w) * sA.w + mA.w);
    }
    short8 bfr[7];
#pragma unroll
    for (int nt = 0; nt < 7; ++nt)
      bfr[nt] = *reinterpret_cast<const short8*>(wp + (long)nt * 16 * 320 + k0);
#pragma unroll
    for (int nt = 0; nt < 7; ++nt)
      acc[nt] = __builtin_amdgcn_mfma_f32_16x16x32_bf16(af, bfr[nt], acc[nt], 0, 0, 0);
  }

#pragma unroll
  for (int nt = 0; nt < 7; ++nt) {
    int col = nt * 16 + r;
    float bias = (col < 100) ? b2[col] : 0.f;
    float ps = 0.f, pq = 0.f;
#pragma unroll
    for (int v = 0; v < 4; ++v) {
      float val = fmaxf(acc[nt][v] + bias, 0.f);
      h2[(rowb + g * 4 + v) * 112 + col] = f2b(val);     // padded cols store 0
      ps += val; pq += val * val;
    }
    float ts = ps + __shfl_xor(ps, 16, 64); ts += __shfl_xor(ts, 32, 64);
    float tq = pq + __shfl_xor(pq, 16, 64); tq += __shfl_xor(tq, 32, 64);
    if (g == 0) { atomicAdd(&sum2[col], ts); atomicAdd(&sq2[col], tq); }
  }
}

// ------- GEMM3: out = ((a2*h2+c2)*s2+m2) @ W3^T + b3 -------
__global__ __launch_bounds__(512, 2) void k_gemm3(
    const unsigned short* __restrict__ h2, const float* __restrict__ s2,
    const float* __restrict__ m2, const float* __restrict__ a2,
    const float* __restrict__ c2, const float* __restrict__ b3,
    const unsigned short* __restrict__ w3bf,
    float* __restrict__ out) {
  const int lane = threadIdx.x & 63, wid = threadIdx.x >> 6;
  const int r = lane & 15, g = lane >> 4;
  const long rowb = (long)blockIdx.x * 128 + wid * 16;
  const long row = rowb + r;

  f32x4 acc = {};
  const unsigned short* hp = h2 + row * 112 + g * 8;
  const float* sp = s2 + row * 100 + g * 8;
  const float* mp = m2 + row * 100 + g * 8;
  const unsigned short* wp = w3bf + (long)r * 112 + g * 8;

  for (int k0 = 0; k0 < 112; k0 += 32) {
    int kb = k0 + g * 8;
    short8 af = (short8)(short)0;
    if (kb + 8 <= 100) {
      short8 h8 = *reinterpret_cast<const short8*>(hp + k0);
      float4 sA = *reinterpret_cast<const float4*>(sp + k0);
      float4 sB = *reinterpret_cast<const float4*>(sp + k0 + 4);
      float4 mA = *reinterpret_cast<const float4*>(mp + k0);
      float4 mB = *reinterpret_cast<const float4*>(mp + k0 + 4);
      float4 aA = *reinterpret_cast<const float4*>(a2 + kb);
      float4 aB = *reinterpret_cast<const float4*>(a2 + kb + 4);
      float4 cA = *reinterpret_cast<const float4*>(c2 + kb);
      float4 cB = *reinterpret_cast<const float4*>(c2 + kb + 4);
      af[0] = f2b((aA.x * b2f((unsigned short)h8[0]) + cA.x) * sA.x + mA.x);
      af[1] = f2b((aA.y * b2f((unsigned short)h8[1]) + cA.y) * sA.y + mA.y);
      af[2] = f2b((aA.z * b2f((unsigned short)h8[2]) + cA.z) * sA.z + mA.z);
      af[3] = f2b((aA.w * b2f((unsigned short)h8[3]) + cA.w) * sA.w + mA.w);
      af[4] = f2b((aB.x * b2f((unsigned short)h8[4]) + cB.x) * sB.x + mB.x);
      af[5] = f2b((aB.y * b2f((unsigned short)h8[5]) + cB.y) * sB.y + mB.y);
      af[6] = f2b((aB.z * b2f((unsigned short)h8[6]) + cB.z) * sB.z + mB.z);
      af[7] = f2b((aB.w * b2f((unsigned short)h8[7]) + cB.w) * sB.w + mB.w);
    } else if (kb < 100) {                    // kb == 96: 4 valid
      short8 h8 = *reinterpret_cast<const short8*>(hp + k0);   // cols 96..103 exist
      float4 sA = *reinterpret_cast<const float4*>(sp + k0);
      float4 mA = *reinterpret_cast<const float4*>(mp + k0);
      float4 aA = *reinterpret_cast<const float4*>(a2 + kb);
      float4 cA = *reinterpret_cast<const float4*>(c2 + kb);
      af[0] = f2b((aA.x * b2f((unsigned short)h8[0]) + cA.x) * sA.x + mA.x);
      af[1] = f2b((aA.y * b2f((unsigned short)h8[1]) + cA.y) * sA.y + mA.y);
      af[2] = f2b((aA.z * b2f((unsigned short)h8[2]) + cA.z) * sA.z + mA.z);
      af[3] = f2b((aA.w * b2f((unsigned short)h8[3]) + cA.w) * sA.w + mA.w);
    }
    // B load may run 16B past w3bf for masked groups (reads inside ws; A=0 -> contributes 0)
    short8 bfr = *reinterpret_cast<const short8*>(wp + k0);
    acc = __builtin_amdgcn_mfma_f32_16x16x32_bf16(af, bfr, acc, 0, 0, 0);
  }

  if (r < 10) {
    float bias = b3[r];
#pragma unroll
    for (int v = 0; v < 4; ++v)
      out[(rowb + g * 4 + v) * 10 + r] = acc[v] + bias;
  }
}

extern "C" void kernel_launch(void* const* d_in, const int* in_sizes, int n_in,
                              void* d_out, int out_size, void* d_ws, size_t ws_size,
                              hipStream_t stream) {
  const float* x   = (const float*)d_in[0];
  const float* W1  = (const float*)d_in[1];
  const float* b1  = (const float*)d_in[2];
  const float* g1  = (const float*)d_in[3];
  const float* be1 = (const float*)d_in[4];
  const float* s1  = (const float*)d_in[5];
  const float* m1  = (const float*)d_in[6];
  const float* W2  = (const float*)d_in[7];
  const float* b2  = (const float*)d_in[8];
  const float* g2  = (const float*)d_in[9];
  const float* be2 = (const float*)d_in[10];
  const float* s2  = (const float*)d_in[11];
  const float* m2  = (const float*)d_in[12];
  const float* W3  = (const float*)d_in[13];
  const float* b3  = (const float*)d_in[14];

  char* ws = (char*)d_ws;
  float* sum1 = (float*)(ws + OFF_SUM1);
  float* sq1  = (float*)(ws + OFF_SQ1);
  float* sum2 = (float*)(ws + OFF_SUM2);
  float* sq2  = (float*)(ws + OFF_SQ2);
  float* a1   = (float*)(ws + OFF_A1);
  float* c1   = (float*)(ws + OFF_C1);
  float* a2   = (float*)(ws + OFF_A2);
  float* c2   = (float*)(ws + OFF_C2);
  unsigned short* w1bf = (unsigned short*)(ws + OFF_W1BF);
  unsigned short* w2bf = (unsigned short*)(ws + OFF_W2BF);
  unsigned short* w3bf = (unsigned short*)(ws + OFF_W3BF);
  unsigned short* h1   = (unsigned short*)(ws + OFF_H1);
  unsigned short* h2   = (unsigned short*)(ws + OFF_H2);

  hipMemsetAsync(ws, 0, 3584, stream);                       // zero stats accumulators

  k_prep<<<574, 512, 0, stream>>>(W1, W2, W3, w1bf, w2bf, w3bf);
  k_gemm1<<<512, 512, 0, stream>>>(x, b1, w1bf, h1, sum1, sq1);
  k_finalize<<<1, 512, 0, stream>>>(sum1, sq1, g1, be1, a1, c1, 300, 320);
  k_gemm2<<<512, 512, 0, stream>>>(h1, s1, m1, a1, c1, b2, w2bf, h2, sum2, sq2);
  k_finalize<<<1, 512, 0, stream>>>(sum2, sq2, g2, be2, a2, c2, 100, 128);
  k_gemm3<<<512, 512, 0, stream>>>(h2, s2, m2, a2, c2, b3, w3bf, (float*)d_out);
}

// Round 5
// 646.168 us; speedup vs baseline: 1.0089x; 1.0089x over previous
//
#include <hip/hip_runtime.h>
#include <hip/hip_bf16.h>

typedef __attribute__((ext_vector_type(8))) short short8;
typedef __attribute__((ext_vector_type(4))) float f32x4;

#define EPSV 1e-5f

// ---- workspace layout (byte offsets, all 256-aligned) ----
#define OFF_SUM1   0u          // 320 f32
#define OFF_SQ1    1280u       // 320 f32
#define OFF_SUM2   2560u       // 128 f32
#define OFF_SQ2    3072u       // 128 f32
#define OFF_A1     4096u       // 320 f32
#define OFF_C1     5376u       // 320 f32
#define OFF_A2     6656u       // 128 f32
#define OFF_C2     7168u       // 128 f32
#define OFF_W1T    8192u       // [25][320][32] bf16 = 512000 B (tiled, zero-padded)
#define OFF_W2T    524288u     // [10][112][32] bf16 = 71680 B
#define OFF_W3T    602112u     // [4][16][32]  bf16 = 4096 B
#define OFF_H1     1048576u    // [65536][304] bf16 = 39845888 B
#define OFF_H2     41943040u   // [65536][112] bf16 = 14680064 B (ws end ~56.6 MB)

__device__ __forceinline__ float b2f(unsigned short u) {
  return __uint_as_float(((unsigned int)u) << 16);
}
__device__ __forceinline__ unsigned short f2b(float f) {
  __hip_bfloat16 h = __float2bfloat16(f);   // RNE
  return __builtin_bit_cast(unsigned short, h);
}

// ---------------- prep: pack weights into K-step-tiled bf16 ----------------
// w1t[ks][row][kk]: B-tile for K-step ks is contiguous (320*64 B)
__global__ void k_prep(const float* __restrict__ W1, const float* __restrict__ W2,
                       const float* __restrict__ W3, unsigned short* __restrict__ w1t,
                       unsigned short* __restrict__ w2t, unsigned short* __restrict__ w3t) {
  int i = blockIdx.x * blockDim.x + threadIdx.x;
  const int N1 = 25 * 320 * 32, N2 = 10 * 112 * 32, N3 = 4 * 16 * 32;
  if (i < N1) {
    int ks = i / (320 * 32), rem = i % (320 * 32), row = rem / 32, kk = rem % 32;
    int k = ks * 32 + kk;
    w1t[i] = (row < 300 && k < 784) ? f2b(W1[row * 784 + k]) : (unsigned short)0;
  } else if (i < N1 + N2) {
    int j = i - N1;
    int ks = j / (112 * 32), rem = j % (112 * 32), row = rem / 32, kk = rem % 32;
    int k = ks * 32 + kk;
    w2t[j] = (row < 100 && k < 300) ? f2b(W2[row * 300 + k]) : (unsigned short)0;
  } else if (i < N1 + N2 + N3) {
    int j = i - N1 - N2;
    int ks = j / (16 * 32), rem = j % (16 * 32), row = rem / 32, kk = rem % 32;
    int k = ks * 32 + kk;
    w3t[j] = (row < 10 && k < 100) ? f2b(W3[row * 100 + k]) : (unsigned short)0;
  }
}

// ---------------- finalize BN stats -> per-feature affine ----------------
__global__ void k_finalize(const float* __restrict__ sum, const float* __restrict__ sq,
                           const float* __restrict__ g, const float* __restrict__ be,
                           float* __restrict__ a, float* __restrict__ c, int F, int Fpad) {
  int f = blockIdx.x * blockDim.x + threadIdx.x;
  if (f >= Fpad) return;
  if (f < F) {
    float mean = sum[f] * (1.f / 65536.f);
    float var  = sq[f]  * (1.f / 65536.f) - mean * mean;   // biased, matches jnp.var
    float av   = g[f] * rsqrtf(var + EPSV);
    a[f] = av;
    c[f] = be[f] - mean * av;
  } else { a[f] = 0.f; c[f] = 0.f; }
}

// LDS tile layout: [row][4 chunk-slots of 16B], chunk slot XOR-swizzled by (row&3).
// Write side and read side use the same XOR -> consistent (both-sides rule).
__device__ __forceinline__ unsigned int swz(int row, int c) {
  return (unsigned int)(row * 64 + ((c ^ (row & 3)) << 4));
}

// ---------------- GEMM1: h1 = relu(x @ W1^T + b1), + stats ----------------
// BM=64 rows, BN=320 cols, K=784 (25 steps of 32). 8 waves (2M x 4N).
// A staged f32->bf16 coalesced; B staged from tiled w1t (linear).
__global__ __launch_bounds__(512) void k_gemm1(
    const float* __restrict__ x, const float* __restrict__ b1,
    const unsigned short* __restrict__ w1t,
    unsigned short* __restrict__ h1,
    float* __restrict__ sum1, float* __restrict__ sq1) {
  __shared__ __align__(16) unsigned char ldsA[64 * 64];     // 4 KB
  __shared__ __align__(16) unsigned char ldsB[320 * 64];    // 20 KB
  const int tid = threadIdx.x;
  const int lane = tid & 63, wid = tid >> 6;
  const int wm = wid >> 2, wn = wid & 3;
  const int r = lane & 15, g = lane >> 4;
  const long rowbase = (long)blockIdx.x * 64;

  f32x4 acc[2][5] = {};

  for (int ks = 0; ks < 25; ++ks) {
    // ---- stage A (coalesced float4 x2 -> bf16 -> LDS), threads 0..255 ----
    if (tid < 256) {
      int row = tid >> 2, c = tid & 3;
      int kb = ks * 32 + c * 8;
      short8 v = (short8)(short)0;
      if (kb + 8 <= 784) {
        const float* p = x + (rowbase + row) * 784 + kb;
        float4 f0 = *reinterpret_cast<const float4*>(p);
        float4 f1 = *reinterpret_cast<const float4*>(p + 4);
        v[0] = f2b(f0.x); v[1] = f2b(f0.y); v[2] = f2b(f0.z); v[3] = f2b(f0.w);
        v[4] = f2b(f1.x); v[5] = f2b(f1.y); v[6] = f2b(f1.z); v[7] = f2b(f1.w);
      }
      *reinterpret_cast<short8*>(&ldsA[swz(row, c)]) = v;
    }
    // ---- stage B (linear contiguous from tiled w1t): 1280 slots ----
    {
      const unsigned short* wsrc = w1t + ks * (320 * 32);
      int s = tid;
#pragma unroll
      for (int it = 0; it < 3; ++it) {
        if (it < 2 || s < 1280) {
          short8 v = *reinterpret_cast<const short8*>(wsrc + s * 8);
          *reinterpret_cast<short8*>(&ldsB[swz(s >> 2, s & 3)]) = v;
        }
        s += 512;
      }
    }
    __syncthreads();

    short8 af[2], bfr[5];
#pragma unroll
    for (int mt = 0; mt < 2; ++mt) {
      int row = wm * 32 + mt * 16 + r;
      af[mt] = *reinterpret_cast<const short8*>(&ldsA[swz(row, g)]);
    }
#pragma unroll
    for (int nt = 0; nt < 5; ++nt) {
      int row = wn * 80 + nt * 16 + r;
      bfr[nt] = *reinterpret_cast<const short8*>(&ldsB[swz(row, g)]);
    }
#pragma unroll
    for (int mt = 0; mt < 2; ++mt)
#pragma unroll
      for (int nt = 0; nt < 5; ++nt)
        acc[mt][nt] = __builtin_amdgcn_mfma_f32_16x16x32_bf16(af[mt], bfr[nt], acc[mt][nt], 0, 0, 0);
    __syncthreads();
  }

  // epilogue: +bias, relu, store bf16, per-feature stats
#pragma unroll
  for (int nt = 0; nt < 5; ++nt) {
    int col = wn * 80 + nt * 16 + r;
    float bias = (col < 300) ? b1[col] : 0.f;
    float ps = 0.f, pq = 0.f;
#pragma unroll
    for (int mt = 0; mt < 2; ++mt) {
#pragma unroll
      for (int v = 0; v < 4; ++v) {
        float val = fmaxf(acc[mt][nt][v] + bias, 0.f);
        long row = rowbase + wm * 32 + mt * 16 + g * 4 + v;
        if (col < 304) h1[row * 304 + col] = f2b(val);
        ps += val; pq += val * val;
      }
    }
    float ts = ps + __shfl_xor(ps, 16, 64); ts += __shfl_xor(ts, 32, 64);
    float tq = pq + __shfl_xor(pq, 16, 64); tq += __shfl_xor(tq, 32, 64);
    if (g == 0) { atomicAdd(&sum1[col], ts); atomicAdd(&sq1[col], tq); }
  }
}

// ------- GEMM2: h2 = relu( ((a1*h1+c1)*s1+m1) @ W2^T + b2 ), + stats -------
// BM=128, N=112, K=300->320 (10 steps). 8 waves, each owns 16 rows x full N.
__global__ __launch_bounds__(512) void k_gemm2(
    const unsigned short* __restrict__ h1, const float* __restrict__ s1,
    const float* __restrict__ m1, const float* __restrict__ a1,
    const float* __restrict__ c1, const float* __restrict__ b2,
    const unsigned short* __restrict__ w2t,
    unsigned short* __restrict__ h2,
    float* __restrict__ sum2, float* __restrict__ sq2) {
  __shared__ __align__(16) unsigned char ldsA[128 * 64];   // 8 KB
  __shared__ __align__(16) unsigned char ldsB[112 * 64];   // 7 KB
  const int tid = threadIdx.x, lane = tid & 63, wid = tid >> 6;
  const int r = lane & 15, g = lane >> 4;
  const long rowbase = (long)blockIdx.x * 128;

  f32x4 acc[7] = {};

  for (int ks = 0; ks < 10; ++ks) {
    // ---- stage A' = bf16((a1*h1+c1)*s1+m1): one 16B slot per thread ----
    {
      int row = tid >> 2, c = tid & 3;
      int kb = ks * 32 + c * 8;
      long grow = rowbase + row;
      short8 v = (short8)(short)0;
      if (kb + 8 <= 300) {
        short8 h8 = *reinterpret_cast<const short8*>(h1 + grow * 304 + kb);
        float4 sA = *reinterpret_cast<const float4*>(s1 + grow * 300 + kb);
        float4 sB = *reinterpret_cast<const float4*>(s1 + grow * 300 + kb + 4);
        float4 mA = *reinterpret_cast<const float4*>(m1 + grow * 300 + kb);
        float4 mB = *reinterpret_cast<const float4*>(m1 + grow * 300 + kb + 4);
        float4 aA = *reinterpret_cast<const float4*>(a1 + kb);
        float4 aB = *reinterpret_cast<const float4*>(a1 + kb + 4);
        float4 cA = *reinterpret_cast<const float4*>(c1 + kb);
        float4 cB = *reinterpret_cast<const float4*>(c1 + kb + 4);
        v[0] = f2b(fmaf(fmaf(aA.x, b2f((unsigned short)h8[0]), cA.x), sA.x, mA.x));
        v[1] = f2b(fmaf(fmaf(aA.y, b2f((unsigned short)h8[1]), cA.y), sA.y, mA.y));
        v[2] = f2b(fmaf(fmaf(aA.z, b2f((unsigned short)h8[2]), cA.z), sA.z, mA.z));
        v[3] = f2b(fmaf(fmaf(aA.w, b2f((unsigned short)h8[3]), cA.w), sA.w, mA.w));
        v[4] = f2b(fmaf(fmaf(aB.x, b2f((unsigned short)h8[4]), cB.x), sB.x, mB.x));
        v[5] = f2b(fmaf(fmaf(aB.y, b2f((unsigned short)h8[5]), cB.y), sB.y, mB.y));
        v[6] = f2b(fmaf(fmaf(aB.z, b2f((unsigned short)h8[6]), cB.z), sB.z, mB.z));
        v[7] = f2b(fmaf(fmaf(aB.w, b2f((unsigned short)h8[7]), cB.w), sB.w, mB.w));
      } else if (kb < 300) {   // kb == 296: 4 valid (h1 cols 296..303 exist)
        short8 h8 = *reinterpret_cast<const short8*>(h1 + grow * 304 + kb);
        float4 sA = *reinterpret_cast<const float4*>(s1 + grow * 300 + kb);
        float4 mA = *reinterpret_cast<const float4*>(m1 + grow * 300 + kb);
        float4 aA = *reinterpret_cast<const float4*>(a1 + kb);
        float4 cA = *reinterpret_cast<const float4*>(c1 + kb);
        v[0] = f2b(fmaf(fmaf(aA.x, b2f((unsigned short)h8[0]), cA.x), sA.x, mA.x));
        v[1] = f2b(fmaf(fmaf(aA.y, b2f((unsigned short)h8[1]), cA.y), sA.y, mA.y));
        v[2] = f2b(fmaf(fmaf(aA.z, b2f((unsigned short)h8[2]), cA.z), sA.z, mA.z));
        v[3] = f2b(fmaf(fmaf(aA.w, b2f((unsigned short)h8[3]), cA.w), sA.w, mA.w));
      }
      *reinterpret_cast<short8*>(&ldsA[swz(row, c)]) = v;
    }
    // ---- stage B: 448 slots, waves 0..6 ----
    if (wid < 7) {
      int s = wid * 64 + lane;
      short8 v = *reinterpret_cast<const short8*>(w2t + ks * (112 * 32) + s * 8);
      *reinterpret_cast<short8*>(&ldsB[swz(s >> 2, s & 3)]) = v;
    }
    __syncthreads();

    int arow = wid * 16 + r;
    short8 af = *reinterpret_cast<const short8*>(&ldsA[swz(arow, g)]);
#pragma unroll
    for (int nt = 0; nt < 7; ++nt) {
      int brow = nt * 16 + r;
      short8 bfr = *reinterpret_cast<const short8*>(&ldsB[swz(brow, g)]);
      acc[nt] = __builtin_amdgcn_mfma_f32_16x16x32_bf16(af, bfr, acc[nt], 0, 0, 0);
    }
    __syncthreads();
  }

  const long rowb = rowbase + wid * 16;
#pragma unroll
  for (int nt = 0; nt < 7; ++nt) {
    int col = nt * 16 + r;
    float bias = (col < 100) ? b2[col] : 0.f;
    float ps = 0.f, pq = 0.f;
#pragma unroll
    for (int v = 0; v < 4; ++v) {
      float val = fmaxf(acc[nt][v] + bias, 0.f);
      h2[(rowb + g * 4 + v) * 112 + col] = f2b(val);
      ps += val; pq += val * val;
    }
    float ts = ps + __shfl_xor(ps, 16, 64); ts += __shfl_xor(ts, 32, 64);
    float tq = pq + __shfl_xor(pq, 16, 64); tq += __shfl_xor(tq, 32, 64);
    if (g == 0) { atomicAdd(&sum2[col], ts); atomicAdd(&sq2[col], tq); }
  }
}

// ------- GEMM3: out = ((a2*h2+c2)*s2+m2) @ W3^T + b3 -------
// BM=128, N=16, K=100->128 (4 steps).
__global__ __launch_bounds__(512) void k_gemm3(
    const unsigned short* __restrict__ h2, const float* __restrict__ s2,
    const float* __restrict__ m2, const float* __restrict__ a2,
    const float* __restrict__ c2, const float* __restrict__ b3,
    const unsigned short* __restrict__ w3t,
    float* __restrict__ out) {
  __shared__ __align__(16) unsigned char ldsA[128 * 64];   // 8 KB
  __shared__ __align__(16) unsigned char ldsB[16 * 64];    // 1 KB
  const int tid = threadIdx.x, lane = tid & 63, wid = tid >> 6;
  const int r = lane & 15, g = lane >> 4;
  const long rowbase = (long)blockIdx.x * 128;

  f32x4 acc = {};

  for (int ks = 0; ks < 4; ++ks) {
    {
      int row = tid >> 2, c = tid & 3;
      int kb = ks * 32 + c * 8;
      long grow = rowbase + row;
      short8 v = (short8)(short)0;
      if (kb + 8 <= 100) {
        short8 h8 = *reinterpret_cast<const short8*>(h2 + grow * 112 + kb);
        float4 sA = *reinterpret_cast<const float4*>(s2 + grow * 100 + kb);
        float4 sB = *reinterpret_cast<const float4*>(s2 + grow * 100 + kb + 4);
        float4 mA = *reinterpret_cast<const float4*>(m2 + grow * 100 + kb);
        float4 mB = *reinterpret_cast<const float4*>(m2 + grow * 100 + kb + 4);
        float4 aA = *reinterpret_cast<const float4*>(a2 + kb);
        float4 aB = *reinterpret_cast<const float4*>(a2 + kb + 4);
        float4 cA = *reinterpret_cast<const float4*>(c2 + kb);
        float4 cB = *reinterpret_cast<const float4*>(c2 + kb + 4);
        v[0] = f2b(fmaf(fmaf(aA.x, b2f((unsigned short)h8[0]), cA.x), sA.x, mA.x));
        v[1] = f2b(fmaf(fmaf(aA.y, b2f((unsigned short)h8[1]), cA.y), sA.y, mA.y));
        v[2] = f2b(fmaf(fmaf(aA.z, b2f((unsigned short)h8[2]), cA.z), sA.z, mA.z));
        v[3] = f2b(fmaf(fmaf(aA.w, b2f((unsigned short)h8[3]), cA.w), sA.w, mA.w));
        v[4] = f2b(fmaf(fmaf(aB.x, b2f((unsigned short)h8[4]), cB.x), sB.x, mB.x));
        v[5] = f2b(fmaf(fmaf(aB.y, b2f((unsigned short)h8[5]), cB.y), sB.y, mB.y));
        v[6] = f2b(fmaf(fmaf(aB.z, b2f((unsigned short)h8[6]), cB.z), sB.z, mB.z));
        v[7] = f2b(fmaf(fmaf(aB.w, b2f((unsigned short)h8[7]), cB.w), sB.w, mB.w));
      } else if (kb < 100) {   // kb == 96: 4 valid (h2 cols 96..103 exist)
        short8 h8 = *reinterpret_cast<const short8*>(h2 + grow * 112 + kb);
        float4 sA = *reinterpret_cast<const float4*>(s2 + grow * 100 + kb);
        float4 mA = *reinterpret_cast<const float4*>(m2 + grow * 100 + kb);
        float4 aA = *reinterpret_cast<const float4*>(a2 + kb);
        float4 cA = *reinterpret_cast<const float4*>(c2 + kb);
        v[0] = f2b(fmaf(fmaf(aA.x, b2f((unsigned short)h8[0]), cA.x), sA.x, mA.x));
        v[1] = f2b(fmaf(fmaf(aA.y, b2f((unsigned short)h8[1]), cA.y), sA.y, mA.y));
        v[2] = f2b(fmaf(fmaf(aA.z, b2f((unsigned short)h8[2]), cA.z), sA.z, mA.z));
        v[3] = f2b(fmaf(fmaf(aA.w, b2f((unsigned short)h8[3]), cA.w), sA.w, mA.w));
      }
      *reinterpret_cast<short8*>(&ldsA[swz(row, c)]) = v;
    }
    if (wid == 0) {
      int s = lane;
      short8 v = *reinterpret_cast<const short8*>(w3t + ks * (16 * 32) + s * 8);
      *reinterpret_cast<short8*>(&ldsB[swz(s >> 2, s & 3)]) = v;
    }
    __syncthreads();

    int arow = wid * 16 + r;
    short8 af = *reinterpret_cast<const short8*>(&ldsA[swz(arow, g)]);
    short8 bfr = *reinterpret_cast<const short8*>(&ldsB[swz(r, g)]);
    acc = __builtin_amdgcn_mfma_f32_16x16x32_bf16(af, bfr, acc, 0, 0, 0);
    __syncthreads();
  }

  const long rowb = rowbase + wid * 16;
  if (r < 10) {
    float bias = b3[r];
#pragma unroll
    for (int v = 0; v < 4; ++v)
      out[(rowb + g * 4 + v) * 10 + r] = acc[v] + bias;
  }
}

extern "C" void kernel_launch(void* const* d_in, const int* in_sizes, int n_in,
                              void* d_out, int out_size, void* d_ws, size_t ws_size,
                              hipStream_t stream) {
  const float* x   = (const float*)d_in[0];
  const float* W1  = (const float*)d_in[1];
  const float* b1  = (const float*)d_in[2];
  const float* g1  = (const float*)d_in[3];
  const float* be1 = (const float*)d_in[4];
  const float* s1  = (const float*)d_in[5];
  const float* m1  = (const float*)d_in[6];
  const float* W2  = (const float*)d_in[7];
  const float* b2  = (const float*)d_in[8];
  const float* g2  = (const float*)d_in[9];
  const float* be2 = (const float*)d_in[10];
  const float* s2  = (const float*)d_in[11];
  const float* m2  = (const float*)d_in[12];
  const float* W3  = (const float*)d_in[13];
  const float* b3  = (const float*)d_in[14];

  char* ws = (char*)d_ws;
  float* sum1 = (float*)(ws + OFF_SUM1);
  float* sq1  = (float*)(ws + OFF_SQ1);
  float* sum2 = (float*)(ws + OFF_SUM2);
  float* sq2  = (float*)(ws + OFF_SQ2);
  float* a1   = (float*)(ws + OFF_A1);
  float* c1   = (float*)(ws + OFF_C1);
  float* a2   = (float*)(ws + OFF_A2);
  float* c2   = (float*)(ws + OFF_C2);
  unsigned short* w1t = (unsigned short*)(ws + OFF_W1T);
  unsigned short* w2t = (unsigned short*)(ws + OFF_W2T);
  unsigned short* w3t = (unsigned short*)(ws + OFF_W3T);
  unsigned short* h1  = (unsigned short*)(ws + OFF_H1);
  unsigned short* h2  = (unsigned short*)(ws + OFF_H2);

  hipMemsetAsync(ws, 0, 3584, stream);   // zero stats accumulators

  k_prep<<<574, 512, 0, stream>>>(W1, W2, W3, w1t, w2t, w3t);
  k_gemm1<<<1024, 512, 0, stream>>>(x, b1, w1t, h1, sum1, sq1);
  k_finalize<<<1, 512, 0, stream>>>(sum1, sq1, g1, be1, a1, c1, 300, 320);
  k_gemm2<<<512, 512, 0, stream>>>(h1, s1, m1, a1, c1, b2, w2t, h2, sum2, sq2);
  k_finalize<<<1, 512, 0, stream>>>(sum2, sq2, g2, be2, a2, c2, 100, 128);
  k_gemm3<<<512, 512, 0, stream>>>(h2, s2, m2, a2, c2, b3, w3t, (float*)d_out);
}